// Round 1
// baseline (71.750 us; speedup 1.0000x reference)
//
#include <hip/hip_runtime.h>

#define NHEADS 8
#define NPTS 4
#define EDIM 256
#define GRIDW 32
#define LTOK 1024  // 32*32

// Kernel A: per-token offsets/attn GEMV + softmax + bilinear sampling
// out1[token][e] = sum_{h,p,corner} w * query[n, y, x, e]
__global__ __launch_bounds__(256) void deform_sample_kernel(
    const float* __restrict__ query,   // [N,32,32,256] == [N*L, 256]
    const float* __restrict__ refp,    // [N,L,2]
    const float* __restrict__ W_off,   // [256,64]
    const float* __restrict__ b_off,   // [64]
    const float* __restrict__ W_attn,  // [256,32]
    const float* __restrict__ b_attn,  // [32]
    float* __restrict__ out1)          // [N*L,256]
{
    const int token = blockIdx.x;      // n*L + l
    const int n = token >> 10;
    const int tid = threadIdx.x;

    __shared__ float qs[EDIM];
    __shared__ float logits[96];                  // [0..63] offsets, [64..95] attn logits
    __shared__ float cw[NHEADS * NPTS * 4];       // corner weights (attn/8 * bilinear * valid)
    __shared__ int   cidx[NHEADS * NPTS * 4];     // base element offset into query (incl. n)

    qs[tid] = query[token * EDIM + tid];
    __syncthreads();

    // ---- GEMV: 96 logits ----
    if (tid < 64) {
        float a0 = 0.f, a1 = 0.f, a2 = 0.f, a3 = 0.f;
        #pragma unroll 4
        for (int e = 0; e < EDIM; e += 4) {
            a0 = fmaf(qs[e + 0], W_off[(e + 0) * 64 + tid], a0);
            a1 = fmaf(qs[e + 1], W_off[(e + 1) * 64 + tid], a1);
            a2 = fmaf(qs[e + 2], W_off[(e + 2) * 64 + tid], a2);
            a3 = fmaf(qs[e + 3], W_off[(e + 3) * 64 + tid], a3);
        }
        logits[tid] = (a0 + a1) + (a2 + a3) + b_off[tid];
    } else if (tid < 96) {
        const int j = tid - 64;
        float a0 = 0.f, a1 = 0.f, a2 = 0.f, a3 = 0.f;
        #pragma unroll 4
        for (int e = 0; e < EDIM; e += 4) {
            a0 = fmaf(qs[e + 0], W_attn[(e + 0) * 32 + j], a0);
            a1 = fmaf(qs[e + 1], W_attn[(e + 1) * 32 + j], a1);
            a2 = fmaf(qs[e + 2], W_attn[(e + 2) * 32 + j], a2);
            a3 = fmaf(qs[e + 3], W_attn[(e + 3) * 32 + j], a3);
        }
        logits[tid] = (a0 + a1) + (a2 + a3) + b_attn[j];
    }
    __syncthreads();

    // ---- softmax (redundant per-thread, avoids a barrier) + corner precompute ----
    if (tid < 32) {
        const int s = tid;             // s = h*NPTS + p
        const int h = s >> 2;
        // softmax over the 4 points of head h, scaled by 1/NHEADS
        const float l0 = logits[64 + h * 4 + 0];
        const float l1 = logits[64 + h * 4 + 1];
        const float l2 = logits[64 + h * 4 + 2];
        const float l3 = logits[64 + h * 4 + 3];
        const float m  = fmaxf(fmaxf(l0, l1), fmaxf(l2, l3));
        const float e0 = __expf(l0 - m), e1 = __expf(l1 - m),
                    e2 = __expf(l2 - m), e3 = __expf(l3 - m);
        const float denom = e0 + e1 + e2 + e3;
        const float mylogit = logits[64 + s];
        const float aw = __expf(mylogit - m) / (denom * (float)NHEADS);

        // sampling location
        const float rx = refp[token * 2 + 0];
        const float ry = refp[token * 2 + 1];
        const float ox = logits[2 * s + 0];
        const float oy = logits[2 * s + 1];
        const float x = (rx + ox) * 32.0f - 0.5f;
        const float y = (ry + oy) * 32.0f - 0.5f;
        const float x0f = floorf(x);
        const float y0f = floorf(y);
        const float wx = x - x0f;
        const float wy = y - y0f;
        const int x0 = (int)x0f;
        const int y0 = (int)y0f;

        const int xi[4] = { x0, x0 + 1, x0, x0 + 1 };
        const int yi[4] = { y0, y0, y0 + 1, y0 + 1 };
        const float wc[4] = { (1.f - wx) * (1.f - wy), wx * (1.f - wy),
                              (1.f - wx) * wy,         wx * wy };
        #pragma unroll
        for (int c = 0; c < 4; ++c) {
            const bool valid = (xi[c] >= 0) & (xi[c] < GRIDW) & (yi[c] >= 0) & (yi[c] < GRIDW);
            cw[s * 4 + c]   = valid ? (wc[c] * aw) : 0.f;
            cidx[s * 4 + c] = valid ? ((n * LTOK + yi[c] * GRIDW + xi[c]) * EDIM) : 0;
        }
    }
    __syncthreads();

    // ---- gather-accumulate: 128 taps, each a contiguous 256-float row ----
    float acc = 0.f;
    #pragma unroll 4
    for (int s = 0; s < NHEADS * NPTS * 4; ++s) {
        acc = fmaf(cw[s], query[cidx[s] + tid], acc);
    }
    out1[token * EDIM + tid] = acc;
}

// Kernel B: out = out1 @ W_out + b_out   ([4096,256] @ [256,256], f32 vector FMA)
__global__ __launch_bounds__(256) void proj_kernel(
    const float* __restrict__ A,      // [4096,256]
    const float* __restrict__ W,      // [256,256]
    const float* __restrict__ b,      // [256]
    float* __restrict__ out)          // [4096,256]
{
    const int rb = blockIdx.x * 16;
    const int c = threadIdx.x;
    __shared__ float As[16][EDIM];

    #pragma unroll
    for (int r = 0; r < 16; ++r) As[r][c] = A[(rb + r) * EDIM + c];
    __syncthreads();

    float acc[16];
    #pragma unroll
    for (int r = 0; r < 16; ++r) acc[r] = 0.f;

    for (int e = 0; e < EDIM; e += 4) {
        const float w0 = W[(e + 0) * EDIM + c];
        const float w1 = W[(e + 1) * EDIM + c];
        const float w2 = W[(e + 2) * EDIM + c];
        const float w3 = W[(e + 3) * EDIM + c];
        #pragma unroll
        for (int r = 0; r < 16; ++r) {
            const float4 a = *reinterpret_cast<const float4*>(&As[r][e]);
            float t = fmaf(a.x, w0, acc[r]);
            t = fmaf(a.y, w1, t);
            t = fmaf(a.z, w2, t);
            acc[r] = fmaf(a.w, w3, t);
        }
    }

    const float bias = b[c];
    #pragma unroll
    for (int r = 0; r < 16; ++r) out[(rb + r) * EDIM + c] = acc[r] + bias;
}

extern "C" void kernel_launch(void* const* d_in, const int* in_sizes, int n_in,
                              void* d_out, int out_size, void* d_ws, size_t ws_size,
                              hipStream_t stream) {
    const float* query  = (const float*)d_in[0];
    const float* refp   = (const float*)d_in[1];
    const float* W_off  = (const float*)d_in[2];
    const float* b_off  = (const float*)d_in[3];
    const float* W_attn = (const float*)d_in[4];
    const float* b_attn = (const float*)d_in[5];
    const float* W_out  = (const float*)d_in[6];
    const float* b_out  = (const float*)d_in[7];
    float* out = (float*)d_out;

    float* out1 = (float*)d_ws;   // 4096*256 f32 = 4 MB scratch

    const int ntok = 4 * LTOK;    // 4096
    deform_sample_kernel<<<ntok, 256, 0, stream>>>(query, refp, W_off, b_off,
                                                   W_attn, b_attn, out1);
    proj_kernel<<<ntok / 16, 256, 0, stream>>>(out1, W_out, b_out, out);
}